// Round 1
// baseline (221.269 us; speedup 1.0000x reference)
//
#include <hip/hip_runtime.h>

// Problem constants (fixed by the reference).
#define R_   512
#define K_   17
#define HIN  56
#define WIN  56
#define OUTS 96          // ROI_H == ROI_W
#define NMAP (R_ * K_)   // 8704

__device__ __forceinline__ float cubicw(float x) {
    const float A = -0.75f;
    x = fabsf(x);
    float nearw = ((A + 2.0f) * x - (A + 3.0f)) * x * x + 1.0f;
    float farw  = A * (((x - 5.0f) * x + 8.0f) * x - 4.0f);
    return x <= 1.0f ? nearw : (x < 2.0f ? farw : 0.0f);
}

__global__ __launch_bounds__(256)
void _Keypointer_kernel(const float* __restrict__ masks,
                        const float* __restrict__ boxes,
                        float* __restrict__ out) {
    __shared__ float smask[HIN * WIN];            // 3136 f  (12544 B)
    __shared__ float tmp[OUTS * (WIN + 1)];       // 96*57 f (21888 B), +1 pad vs bank conflicts
    __shared__ float wtab[OUTS][4];               // bicubic weights (shared for y and x: My==Mx)
    __shared__ int   itab[OUTS][4];               // clamped tap indices
    __shared__ float redv[4];
    __shared__ int   redp[4];

    const int t   = threadIdx.x;
    const int map = blockIdx.x;                   // r*K + k

    // --- per-block tap tables (96 rows, 4 taps each) ---
    if (t < OUTS) {
        float src  = ((float)t + 0.5f) * (56.0f / 96.0f) - 0.5f;
        int   base = (int)floorf(src);
#pragma unroll
        for (int q = 0; q < 4; ++q) {
            int tap = base - 1 + q;
            wtab[t][q] = cubicw(src - (float)tap);   // weight from UNclamped distance
            itab[t][q] = min(max(tap, 0), HIN - 1);  // replicate border
        }
    }

    // --- stage mask [56,56] into LDS, float4-coalesced (12544 B, 16B-aligned per map) ---
    const float4* msrc = (const float4*)(masks + (size_t)map * (HIN * WIN));
    float4*       mdst = (float4*)smask;
#pragma unroll 2
    for (int i = t; i < (HIN * WIN) / 4; i += 256) mdst[i] = msrc[i];
    __syncthreads();

    // --- pass 1: tmp[h][j] = sum_q wy[h][q] * mask[iy[h][q]][j]   (96x56 outputs) ---
    for (int o = t; o < OUTS * WIN; o += 256) {
        int h = o / WIN;
        int j = o - h * WIN;
        float acc = 0.0f;
#pragma unroll
        for (int q = 0; q < 4; ++q)
            acc += wtab[h][q] * smask[itab[h][q] * WIN + j];
        tmp[h * (WIN + 1) + j] = acc;
    }
    __syncthreads();

    // --- pass 2: out[h][w] = sum_q wx[w][q] * tmp[h][ix[w][q]], fused running argmax ---
    float best  = -INFINITY;
    int   bestp = 0x7fffffff;
    for (int o = t; o < OUTS * OUTS; o += 256) {
        int h = o / OUTS;
        int w = o - h * OUTS;
        const float* trow = tmp + h * (WIN + 1);
        float acc = 0.0f;
#pragma unroll
        for (int q = 0; q < 4; ++q)
            acc += wtab[w][q] * trow[itab[w][q]];
        // strict > keeps the earliest (smallest o) on exact ties, matching jnp.argmax
        if (acc > best) { best = acc; bestp = o; }
    }

    // --- wave-64 argmax reduce (value desc, index asc on ties) ---
#pragma unroll
    for (int off = 32; off > 0; off >>= 1) {
        float ov = __shfl_down(best, off, 64);
        int   op = __shfl_down(bestp, off, 64);
        if (ov > best || (ov == best && op < bestp)) { best = ov; bestp = op; }
    }
    const int wave = t >> 6, lane = t & 63;
    if (lane == 0) { redv[wave] = best; redp[wave] = bestp; }
    __syncthreads();

    if (t == 0) {
#pragma unroll
        for (int i = 1; i < 4; ++i)
            if (redv[i] > best || (redv[i] == best && redp[i] < bestp)) {
                best = redv[i]; bestp = redp[i];
            }
        const int r = map / K_, k = map - r * K_;
        const int y = bestp / OUTS, x = bestp - y * OUTS;

        const float b0 = boxes[r * 4 + 0], b1 = boxes[r * 4 + 1];
        const float b2 = boxes[r * 4 + 2], b3 = boxes[r * 4 + 3];
        const float corr0 = fmaxf(b2 - b0, 1.0f) / (float)OUTS;
        const float corr1 = fmaxf(b3 - b1, 1.0f) / (float)OUTS;
        const float p0 = ((float)y + 0.5f) * corr0 + b0;
        const float p1 = ((float)x + 0.5f) * corr1 + b1;

        // predictions [R, 3, K] then scores [R, K], concatenated flat
        out[(r * 3 + 0) * K_ + k] = p0;
        out[(r * 3 + 1) * K_ + k] = p1;
        out[(r * 3 + 2) * K_ + k] = 1.0f;
        out[R_ * 3 * K_ + r * K_ + k] = best;
    }
}

extern "C" void kernel_launch(void* const* d_in, const int* in_sizes, int n_in,
                              void* d_out, int out_size, void* d_ws, size_t ws_size,
                              hipStream_t stream) {
    const float* masks = (const float*)d_in[0];
    const float* boxes = (const float*)d_in[1];
    float* out = (float*)d_out;
    _Keypointer_kernel<<<NMAP, 256, 0, stream>>>(masks, boxes, out);
}

// Round 3
// 189.713 us; speedup vs baseline: 1.1663x; 1.1663x over previous
//
#include <hip/hip_runtime.h>

#define R_   512
#define K_   17
#define HIN  56
#define WIN  56
#define OUTS 96
#define NMAP (R_ * K_)
#define NT   192            // 3 waves; 96 divides 192, 1344 pass-1 quads = 7*192

__device__ __forceinline__ float cubicw(float x) {
    const float A = -0.75f;
    x = fabsf(x);
    float nearw = ((A + 2.0f) * x - (A + 3.0f)) * x * x + 1.0f;
    float farw  = A * (((x - 5.0f) * x + 8.0f) * x - 4.0f);
    return x <= 1.0f ? nearw : (x < 2.0f ? farw : 0.0f);
}

__global__ __launch_bounds__(NT)
void _Keypointer_kernel(const float* __restrict__ masks,
                        const float* __restrict__ boxes,
                        float* __restrict__ out) {
    __shared__ float  smask[HIN * WIN];     // 12544 B
    __shared__ float  tmp[OUTS * WIN];      // 21504 B (row stride 56 floats, f4-aligned)
    __shared__ float4 wy4[OUTS];            // y-pass raw weights
    __shared__ int4   iy4[OUTS];            // y-pass clamped taps
    __shared__ float4 wx4[OUTS];            // x-pass EFFECTIVE weights on window
    __shared__ int    sx[OUTS];             // x-pass window start (0..52)
    __shared__ float  redv[NT / 64];
    __shared__ int    redp[NT / 64];

    const int t   = threadIdx.x;
    const int map = blockIdx.x;

    // ---- per-block tap tables (same src grid for y and x since 96x56 both ways) ----
    if (t < OUTS) {
        float src  = ((float)t + 0.5f) * (56.0f / 96.0f) - 0.5f;
        int   base = (int)floorf(src);
        float w0 = cubicw(src - (float)(base - 1));
        float w1 = cubicw(src - (float)(base + 0));
        float w2 = cubicw(src - (float)(base + 1));
        float w3 = cubicw(src - (float)(base + 2));
        // y tables: clamped taps, raw weights (identical rounding to round-1 kernel)
        iy4[t] = make_int4(min(max(base - 1, 0), HIN - 1),
                           min(max(base + 0, 0), HIN - 1),
                           min(max(base + 1, 0), HIN - 1),
                           min(max(base + 2, 0), HIN - 1));
        wy4[t] = make_float4(w0, w1, w2, w3);
        // x tables: fold clamping into effective weights on contiguous window [s, s+3]
        int s = min(max(base - 1, 0), WIN - 4);
        float eff[4] = {0.f, 0.f, 0.f, 0.f};
        float wq[4] = {w0, w1, w2, w3};
#pragma unroll
        for (int q = 0; q < 4; ++q) {
            int p = min(max(base - 1 + q, 0), WIN - 1);
            eff[p - s] += wq[q];            // interior: eff[q] = wq[q] exactly
        }
        wx4[t] = make_float4(eff[0], eff[1], eff[2], eff[3]);
        sx[t]  = s;
    }

    // ---- stage mask into LDS (784 float4) ----
    const float4* msrc = (const float4*)(masks + (size_t)map * (HIN * WIN));
    float4*       mdst = (float4*)smask;
    for (int i = t; i < (HIN * WIN) / 4; i += NT) mdst[i] = msrc[i];
    __syncthreads();

    // ---- pass 1 (y): tmp[h][j] = sum_q wy[h][q] * smask[iy[h][q]][j], float4 over j ----
    const float4* sm4  = (const float4*)smask;
    float4*       tmp4 = (float4*)tmp;
#pragma unroll
    for (int i = 0; i < 7; ++i) {           // 1344 quad-units = 7 * 192
        int u  = t + NT * i;
        int h  = u / 14;                    // 14 quads per row
        int jq = u - h * 14;
        float4 W  = wy4[h];
        int4   tp = iy4[h];
        float4 m0 = sm4[tp.x * 14 + jq];
        float4 m1 = sm4[tp.y * 14 + jq];
        float4 m2 = sm4[tp.z * 14 + jq];
        float4 m3 = sm4[tp.w * 14 + jq];
        float4 a;
        a.x = fmaf(W.w, m3.x, fmaf(W.z, m2.x, fmaf(W.y, m1.x, W.x * m0.x)));
        a.y = fmaf(W.w, m3.y, fmaf(W.z, m2.y, fmaf(W.y, m1.y, W.x * m0.y)));
        a.z = fmaf(W.w, m3.z, fmaf(W.z, m2.z, fmaf(W.y, m1.z, W.x * m0.z)));
        a.w = fmaf(W.w, m3.w, fmaf(W.z, m2.w, fmaf(W.y, m1.w, W.x * m0.w)));
        tmp4[h * 14 + jq] = a;
    }
    __syncthreads();

    // ---- pass 2 (x) + fused argmax: fixed w per thread, loop h, no division ----
    const int w_ = (t >= 96) ? t - 96 : t;  // column owned by this thread
    const int g  = (t >= 96) ? 1 : 0;       // row parity group
    const float4 W = wx4[w_];
    const float* p = tmp + g * WIN + sx[w_];
    float best  = -INFINITY;
    int   bestp = 0x7fffffff;
    int   pos   = g * OUTS + w_;
#pragma unroll 6
    for (int it = 0; it < OUTS / 2; ++it) { // h = g, g+2, ..., g+94
        float t0 = p[0], t1 = p[1], t2 = p[2], t3 = p[3];
        float acc = fmaf(W.w, t3, fmaf(W.z, t2, fmaf(W.y, t1, W.x * t0)));
        if (acc > best) { best = acc; bestp = pos; }
        pos += 2 * OUTS;
        p   += 2 * WIN;
    }

    // ---- argmax reduce: wave-64 shuffle, then 3-wave LDS merge ----
#pragma unroll
    for (int off = 32; off > 0; off >>= 1) {
        float ov = __shfl_down(best, off, 64);
        int   op = __shfl_down(bestp, off, 64);
        if (ov > best || (ov == best && op < bestp)) { best = ov; bestp = op; }
    }
    const int wave = t >> 6, lane = t & 63;
    if (lane == 0) { redv[wave] = best; redp[wave] = bestp; }
    __syncthreads();

    if (t == 0) {
#pragma unroll
        for (int i = 1; i < NT / 64; ++i)
            if (redv[i] > best || (redv[i] == best && redp[i] < bestp)) {
                best = redv[i]; bestp = redp[i];
            }
        const int r = map / K_, k = map - r * K_;
        const int y = bestp / OUTS, x = bestp - y * OUTS;

        const float b0 = boxes[r * 4 + 0], b1 = boxes[r * 4 + 1];
        const float b2 = boxes[r * 4 + 2], b3 = boxes[r * 4 + 3];
        const float corr0 = fmaxf(b2 - b0, 1.0f) / (float)OUTS;
        const float corr1 = fmaxf(b3 - b1, 1.0f) / (float)OUTS;
        const float p0 = ((float)y + 0.5f) * corr0 + b0;
        const float p1 = ((float)x + 0.5f) * corr1 + b1;

        out[(r * 3 + 0) * K_ + k] = p0;
        out[(r * 3 + 1) * K_ + k] = p1;
        out[(r * 3 + 2) * K_ + k] = 1.0f;
        out[R_ * 3 * K_ + r * K_ + k] = best;
    }
}

extern "C" void kernel_launch(void* const* d_in, const int* in_sizes, int n_in,
                              void* d_out, int out_size, void* d_ws, size_t ws_size,
                              hipStream_t stream) {
    const float* masks = (const float*)d_in[0];
    const float* boxes = (const float*)d_in[1];
    float* out = (float*)d_out;
    _Keypointer_kernel<<<NMAP, NT, 0, stream>>>(masks, boxes, out);
}

// Round 4
// 168.712 us; speedup vs baseline: 1.3115x; 1.1245x over previous
//
#include <hip/hip_runtime.h>

#define R_   512
#define K_   17
#define HIN  56
#define WIN  56
#define OUTS 96
#define NMAP (R_ * K_)
#define NT   96
#define TST  97            // txm row stride in floats (+1 pad -> conflict-free b32)

// Compile-time resize table: window start s[o] (0..52) and 4 effective weights
// (border clamp folded in, duplicate taps accumulated exactly like the
// reference's scatter-add). All float math replicates the reference in f32.
struct Tab {
    float w[OUTS][4];
    int   s[OUTS];
    constexpr Tab() : w{}, s{} {
        for (int o = 0; o < OUTS; ++o) {
            float src = ((float)o + 0.5f) * (56.0f / 96.0f) - 0.5f;
            int base = (int)src;
            if ((float)base > src) --base;          // floor (src > -1 always)
            int st = base - 1;
            if (st < 0) st = 0;
            if (st > HIN - 4) st = HIN - 4;
            s[o] = st;
            for (int q = 0; q < 4; ++q) {
                int tap = base - 1 + q;
                float x = src - (float)tap;
                if (x < 0.0f) x = -x;
                const float A = -0.75f;
                float wt;
                if (x <= 1.0f)     wt = ((A + 2.0f) * x - (A + 3.0f)) * x * x + 1.0f;
                else if (x < 2.0f) wt = A * (((x - 5.0f) * x + 8.0f) * x - 4.0f);
                else               wt = 0.0f;
                int p = tap;
                if (p < 0) p = 0;
                if (p > HIN - 1) p = HIN - 1;
                w[o][p - st] += wt;                  // fold border clamp
            }
        }
    }
};
constexpr Tab TAB;

__global__ __launch_bounds__(NT)
void _Keypointer_kernel(const float* __restrict__ masks,
                        const float* __restrict__ boxes,
                        float* __restrict__ out) {
    __shared__ float txm[HIN * TST];   // x-resized map, [j][w] stride 97 (21728 B)
    __shared__ float redv[2];
    __shared__ int   redp[2];

    const int t   = threadIdx.x;
    const int map = blockIdx.x;

    // ---- phase 1: x-resize. thread j owns input row j, all from registers ----
    if (t < HIN) {
        float r[WIN];
        const float4* g = (const float4*)(masks + (size_t)map * (HIN * WIN) + t * WIN);
#pragma unroll
        for (int i = 0; i < WIN / 4; ++i) {
            float4 v = g[i];
            r[4 * i + 0] = v.x; r[4 * i + 1] = v.y;
            r[4 * i + 2] = v.z; r[4 * i + 3] = v.w;
        }
        float* dst = txm + t * TST;
#pragma unroll
        for (int o = 0; o < OUTS; ++o) {            // compile-time s/w -> static reg idx
            const int   s  = TAB.s[o];
            const float w0 = TAB.w[o][0], w1 = TAB.w[o][1];
            const float w2 = TAB.w[o][2], w3 = TAB.w[o][3];
            dst[o] = fmaf(w3, r[s + 3], fmaf(w2, r[s + 2], fmaf(w1, r[s + 1], w0 * r[s])));
        }
    }
    __syncthreads();

    // ---- phase 2: y-resize + argmax. thread w owns output column w ----
    float c[HIN];
    {
        const float* sp = txm + t;
#pragma unroll
        for (int j = 0; j < HIN; ++j) c[j] = sp[j * TST];   // pairable ds_read2_b32
    }
    float best  = -INFINITY;
    int   bestp = 0x7fffffff;
#pragma unroll
    for (int h = 0; h < OUTS; ++h) {
        const int   s  = TAB.s[h];
        const float w0 = TAB.w[h][0], w1 = TAB.w[h][1];
        const float w2 = TAB.w[h][2], w3 = TAB.w[h][3];
        float acc = fmaf(w3, c[s + 3], fmaf(w2, c[s + 2], fmaf(w1, c[s + 1], w0 * c[s])));
        if (acc > best) { best = acc; bestp = h * OUTS + t; }   // strict >: earliest flat pos
    }

    // ---- reduce: wave0 full 64, wave1 has 32 active lanes ----
    if (t < 64) {
        float ov = __shfl_down(best, 32, 64);
        int   op = __shfl_down(bestp, 32, 64);
        if (ov > best || (ov == best && op < bestp)) { best = ov; bestp = op; }
    }
#pragma unroll
    for (int off = 16; off > 0; off >>= 1) {
        float ov = __shfl_down(best, off, 64);
        int   op = __shfl_down(bestp, off, 64);
        if (ov > best || (ov == best && op < bestp)) { best = ov; bestp = op; }
    }
    if ((t & 63) == 0) { redv[t >> 6] = best; redp[t >> 6] = bestp; }
    __syncthreads();

    if (t == 0) {
        if (redv[1] > best || (redv[1] == best && redp[1] < bestp)) {
            best = redv[1]; bestp = redp[1];
        }
        const int r = map / K_, k = map - r * K_;
        const int y = bestp / OUTS, x = bestp - y * OUTS;

        const float b0 = boxes[r * 4 + 0], b1 = boxes[r * 4 + 1];
        const float b2 = boxes[r * 4 + 2], b3 = boxes[r * 4 + 3];
        const float corr0 = fmaxf(b2 - b0, 1.0f) / (float)OUTS;
        const float corr1 = fmaxf(b3 - b1, 1.0f) / (float)OUTS;
        const float p0 = ((float)y + 0.5f) * corr0 + b0;
        const float p1 = ((float)x + 0.5f) * corr1 + b1;

        out[(r * 3 + 0) * K_ + k] = p0;
        out[(r * 3 + 1) * K_ + k] = p1;
        out[(r * 3 + 2) * K_ + k] = 1.0f;
        out[R_ * 3 * K_ + r * K_ + k] = best;
    }
}

extern "C" void kernel_launch(void* const* d_in, const int* in_sizes, int n_in,
                              void* d_out, int out_size, void* d_ws, size_t ws_size,
                              hipStream_t stream) {
    const float* masks = (const float*)d_in[0];
    const float* boxes = (const float*)d_in[1];
    float* out = (float*)d_out;
    _Keypointer_kernel<<<NMAP, NT, 0, stream>>>(masks, boxes, out);
}

// Round 5
// 161.189 us; speedup vs baseline: 1.3727x; 1.0467x over previous
//
#include <hip/hip_runtime.h>

#define R_    512
#define K_    17
#define HIN   56
#define WIN   56
#define OUTS  96
#define NMAP  (R_ * K_)
#define NT    192
#define TS    98          // tmp row stride in floats (even for b64; 98%32=2 staggers banks)
#define TROWS 32          // 32 tmp rows per map per half (incl. replicate pads)

typedef float v2f __attribute__((ext_vector_type(2)));

constexpr float cubic_c(float xin) {
    float x = xin < 0.0f ? -xin : xin;
    const float A = -0.75f;
    if (x <= 1.0f) return ((A + 2.0f) * x - (A + 3.0f)) * x * x + 1.0f;
    if (x < 2.0f)  return A * (((x - 5.0f) * x + 8.0f) * x - 4.0f);
    return 0.0f;
}

// X-pass (per-row, 96 outputs): folded effective weights on contiguous window [s,s+3].
struct XTabT {
    float w[OUTS][4];
    int   s[OUTS];
    constexpr XTabT() : w{}, s{} {
        for (int o = 0; o < OUTS; ++o) {
            float src = ((float)o + 0.5f) * (56.0f / 96.0f) - 0.5f;
            int base = (int)src;
            if ((float)base > src) --base;
            int st = base - 1;
            if (st < 0) st = 0;
            if (st > HIN - 4) st = HIN - 4;
            s[o] = st;
            for (int q = 0; q < 4; ++q) {
                int tap = base - 1 + q;
                float wt = cubic_c(src - (float)tap);
                int p = tap < 0 ? 0 : (tap > HIN - 1 ? HIN - 1 : tap);
                w[o][p - st] += wt;
            }
        }
    }
};
constexpr XTabT XT;

// Y-pass: period-12 raw weights + relative tap offsets (s~(h)=7*(h/12)+d[h%12]).
// Border clamp handled by replicated pad rows in tmp, so raw taps are always valid.
struct YTabT {
    float w[12][4];
    int   d[12];
    constexpr YTabT() : w{}, d{} {
        for (int ph = 0; ph < 12; ++ph) {
            float src = ((float)ph + 0.5f) * (56.0f / 96.0f) - 0.5f;
            int base = (int)src;
            if ((float)base > src) --base;
            d[ph] = base - 1;                       // in [-2, 5]
            for (int q = 0; q < 4; ++q)
                w[ph][q] = cubic_c(src - (float)(base - 1 + q));
        }
    }
};
constexpr YTabT YT;

// ---- phase 1: x-resize one input row (32 output cols per unit, G = col group) ----
template<int G>
__device__ __forceinline__ void p1_row(const float* __restrict__ gsrc, float out[32]) {
    constexpr int FS = (G == 0) ? 0 : (G == 1) ? 4 : 9;   // first float4 of window
    constexpr int NF = (G == 1) ? 6 : 5;                  // float4 count
    float r[NF * 4];
    const float4* g4 = (const float4*)gsrc + FS;
#pragma unroll
    for (int i = 0; i < NF; ++i) {
        float4 v = g4[i];
        r[4*i+0] = v.x; r[4*i+1] = v.y; r[4*i+2] = v.z; r[4*i+3] = v.w;
    }
#pragma unroll
    for (int oo = 0; oo < 32; ++oo) {
        const int o  = 32 * G + oo;
        const int rs = XT.s[o] - 4 * FS;
        out[oo] = fmaf(XT.w[o][3], r[rs+3], fmaf(XT.w[o][2], r[rs+2],
                  fmaf(XT.w[o][1], r[rs+1], XT.w[o][0] * r[rs])));
    }
}

__device__ __forceinline__ void p1_phase(const float* __restrict__ masks, float* tbase,
                                         int t, int bm0, int j0, bool lowhalf) {
    const int g = t >> 6;                 // wave-uniform column group
    const int w = t & 63;
    if (w >= 60) return;                  // 60 units per wave: 2 maps x 30 rows
    const int mi = w / 30;
    const int jr = w - 30 * mi;
    const int j  = j0 + jr;
    const float* gsrc = masks + (size_t)(bm0 + mi) * (HIN * WIN) + j * WIN;
    float out[32];
    if      (g == 0) p1_row<0>(gsrc, out);
    else if (g == 1) p1_row<1>(gsrc, out);
    else             p1_row<2>(gsrc, out);
    const int phys = lowhalf ? jr + 2 : jr;     // low half stores logical rows -2..29
    float* dst = tbase + mi * (TROWS * TS) + phys * TS + 32 * g;
#pragma unroll
    for (int i = 0; i < 16; ++i) ((v2f*)dst)[i] = (v2f){out[2*i], out[2*i+1]};
    if (lowhalf && jr == 0) {                   // replicate border rows -2,-1 := row 0
        float* d0 = tbase + mi * (TROWS * TS) + 32 * g;
#pragma unroll
        for (int i = 0; i < 16; ++i) {
            v2f v = (v2f){out[2*i], out[2*i+1]};
            ((v2f*)d0)[i] = v;
            ((v2f*)(d0 + TS))[i] = v;
        }
    }
    if (!lowhalf && jr == 29) {                 // replicate rows 56,57 := row 55
        float* d0 = tbase + mi * (TROWS * TS) + 30 * TS + 32 * g;
#pragma unroll
        for (int i = 0; i < 16; ++i) {
            v2f v = (v2f){out[2*i], out[2*i+1]};
            ((v2f*)d0)[i] = v;
            ((v2f*)(d0 + TS))[i] = v;
        }
    }
}

// ---- phase 2: 24 y-outputs for an adjacent column pair, fused argmax ----
__device__ __forceinline__ void p2_block(const float* __restrict__ base, int h0,
                                         float& bx, int& hx, float& by, int& hy) {
    v2f c[18];
#pragma unroll
    for (int i = 0; i < 18; ++i) c[i] = *(const v2f*)(base + i * TS);
#pragma unroll
    for (int hh = 0; hh < 24; ++hh) {
        const int ph = hh % 12;
        const int b  = hh / 12;
        const int i0 = 7 * b + YT.d[ph] + 2;       // in [0,17] by construction
        const v2f w0 = {YT.w[ph][0], YT.w[ph][0]};
        const v2f w1 = {YT.w[ph][1], YT.w[ph][1]};
        const v2f w2 = {YT.w[ph][2], YT.w[ph][2]};
        const v2f w3 = {YT.w[ph][3], YT.w[ph][3]};
        v2f acc = c[i0] * w0;
        acc = __builtin_elementwise_fma(w1, c[i0+1], acc);
        acc = __builtin_elementwise_fma(w2, c[i0+2], acc);
        acc = __builtin_elementwise_fma(w3, c[i0+3], acc);
        const int h = h0 + hh;
        bool gx = acc.x > bx; bx = gx ? acc.x : bx; hx = gx ? h : hx;
        bool gy = acc.y > by; by = gy ? acc.y : by; hy = gy ? h : hy;
    }
}

__global__ __launch_bounds__(NT)
void _Keypointer_kernel(const float* __restrict__ masks,
                        const float* __restrict__ boxes,
                        float* __restrict__ out) {
    __shared__ float tmp[2 * TROWS * TS];   // 25088 B, ping-pong low/high halves
    __shared__ float redv[NT];
    __shared__ int   redp[NT];

    const int t   = threadIdx.x;
    const int bm0 = 2 * blockIdx.x;

    // low half: logical tmp rows -2..29 (x-resize of mask rows 0..29 + pads)
    p1_phase(masks, tmp, t, bm0, 0, true);
    __syncthreads();

    const int mi = t / 96;
    const int v  = t - 96 * mi;
    const int qq = v / 48;                  // quarter-within-half (wave-uniform code)
    const int p  = v - 48 * qq;             // column pair: cols 2p, 2p+1
    const float* pbase = tmp + mi * (TROWS * TS) + (14 * qq) * TS + 2 * p;

    float bx = -INFINITY, by = -INFINITY;
    int hx = 0, hy = 0;
    p2_block(pbase, 24 * qq, bx, hx, by, hy);        // h in [0,47]
    __syncthreads();

    // high half: logical rows 26..57 reuse same buffer (phys = j-26)
    p1_phase(masks, tmp, t, bm0, 26, false);
    __syncthreads();

    p2_block(pbase, 48 + 24 * qq, bx, hx, by, hy);   // h in [48,95]

    // merge the two columns of this thread (tie -> smaller flat pos)
    int fx = hx * OUTS + 2 * p;
    int fy = hy * OUTS + 2 * p + 1;
    if (by > bx || (by == bx && fy < fx)) { bx = by; fx = fy; }
    redv[t] = bx; redp[t] = fx;
    __syncthreads();

    if (t < 64) {
        const int m = t >> 5, i = t & 31;
        const int b0 = m * 96 + i;
        float bv = redv[b0]; int bp = redp[b0];
#pragma unroll
        for (int o = 32; o < 96; o += 32) {
            float vv = redv[b0 + o]; int pp = redp[b0 + o];
            if (vv > bv || (vv == bv && pp < bp)) { bv = vv; bp = pp; }
        }
#pragma unroll
        for (int off = 16; off > 0; off >>= 1) {
            float vv = __shfl_down(bv, off, 32);
            int   pp = __shfl_down(bp, off, 32);
            if (vv > bv || (vv == bv && pp < bp)) { bv = vv; bp = pp; }
        }
        if (i == 0) {
            const int map = bm0 + m;
            const int r = map / K_, k = map - r * K_;
            const int y = bp / OUTS, x = bp - y * OUTS;
            const float b0f = boxes[r * 4 + 0], b1f = boxes[r * 4 + 1];
            const float b2f = boxes[r * 4 + 2], b3f = boxes[r * 4 + 3];
            const float corr0 = fmaxf(b2f - b0f, 1.0f) / (float)OUTS;
            const float corr1 = fmaxf(b3f - b1f, 1.0f) / (float)OUTS;
            const float p0 = ((float)y + 0.5f) * corr0 + b0f;
            const float p1 = ((float)x + 0.5f) * corr1 + b1f;
            out[(r * 3 + 0) * K_ + k] = p0;
            out[(r * 3 + 1) * K_ + k] = p1;
            out[(r * 3 + 2) * K_ + k] = 1.0f;
            out[R_ * 3 * K_ + r * K_ + k] = bv;
        }
    }
}

extern "C" void kernel_launch(void* const* d_in, const int* in_sizes, int n_in,
                              void* d_out, int out_size, void* d_ws, size_t ws_size,
                              hipStream_t stream) {
    const float* masks = (const float*)d_in[0];
    const float* boxes = (const float*)d_in[1];
    float* out = (float*)d_out;
    _Keypointer_kernel<<<NMAP / 2, NT, 0, stream>>>(masks, boxes, out);
}

// Round 6
// 158.335 us; speedup vs baseline: 1.3975x; 1.0180x over previous
//
#include <hip/hip_runtime.h>

#define R_    512
#define K_    17
#define HIN   56
#define WIN   56
#define OUTS  96
#define NMAP  (R_ * K_)
#define NT    192
#define RST   98      // tmp row stride in v2f units (784 B: 16B-aligned, banks stagger by 4)
#define TROWS 60      // phys rows: 0,1 = pad(row0); 2..57 = rows 0..55; 58,59 = pad(row55)

typedef float v2f __attribute__((ext_vector_type(2)));

constexpr float cubic_c(float xin) {
    float x = xin < 0.0f ? -xin : xin;
    const float A = -0.75f;
    if (x <= 1.0f) return ((A + 2.0f) * x - (A + 3.0f)) * x * x + 1.0f;
    if (x < 2.0f)  return A * (((x - 5.0f) * x + 8.0f) * x - 4.0f);
    return 0.0f;
}

// X-pass: folded effective weights on contiguous window [s, s+3] (border clamp folded).
struct XTabT {
    float w[OUTS][4];
    int   s[OUTS];
    constexpr XTabT() : w{}, s{} {
        for (int o = 0; o < OUTS; ++o) {
            float src = ((float)o + 0.5f) * (56.0f / 96.0f) - 0.5f;
            int base = (int)src;
            if ((float)base > src) --base;
            int st = base - 1;
            if (st < 0) st = 0;
            if (st > HIN - 4) st = HIN - 4;
            s[o] = st;
            for (int q = 0; q < 4; ++q) {
                int tap = base - 1 + q;
                float wt = cubic_c(src - (float)tap);
                int p = tap < 0 ? 0 : (tap > HIN - 1 ? HIN - 1 : tap);
                w[o][p - st] += wt;
            }
        }
    }
};
constexpr XTabT XT;

// Y-pass: period-12 raw weights + relative tap start d (logical tap0 row = 7*(h/12)+d[h%12]).
// Border handled by replicated pad rows in tmp (validated: round-5 absmax 0.0).
struct YTabT {
    float w[12][4];
    int   d[12];
    constexpr YTabT() : w{}, d{} {
        for (int ph = 0; ph < 12; ++ph) {
            float src = ((float)ph + 0.5f) * (56.0f / 96.0f) - 0.5f;
            int base = (int)src;
            if ((float)base > src) --base;
            d[ph] = base - 1;
            for (int q = 0; q < 4; ++q)
                w[ph][q] = cubic_c(src - (float)(base - 1 + q));
        }
    }
};
constexpr YTabT YT;

// ---- phase 1: x-resize one row of BOTH maps (32 cols, group G), all pk ops ----
template<int G>
__device__ __forceinline__ void p1_cols(const float* __restrict__ r0,
                                        const float* __restrict__ r1,
                                        v2f* __restrict__ dst) {
    constexpr int FS = (G == 0) ? 0 : (G == 1) ? 4 : 9;   // first float4 of window
    constexpr int NF = (G == 1) ? 6 : 5;
    v2f rr[NF * 4];
    const float4* A = (const float4*)r0 + FS;
    const float4* B = (const float4*)r1 + FS;
#pragma unroll
    for (int i = 0; i < NF; ++i) {
        float4 a = A[i], b = B[i];
        rr[4 * i + 0] = (v2f){a.x, b.x};
        rr[4 * i + 1] = (v2f){a.y, b.y};
        rr[4 * i + 2] = (v2f){a.z, b.z};
        rr[4 * i + 3] = (v2f){a.w, b.w};
    }
#pragma unroll
    for (int i = 0; i < 16; ++i) {
        const int o0 = 32 * G + 2 * i, o1 = o0 + 1;
        const int s0 = XT.s[o0] - 4 * FS, s1 = XT.s[o1] - 4 * FS;
        v2f a0 = rr[s0] * (v2f){XT.w[o0][0], XT.w[o0][0]};
        a0 = __builtin_elementwise_fma((v2f){XT.w[o0][1], XT.w[o0][1]}, rr[s0 + 1], a0);
        a0 = __builtin_elementwise_fma((v2f){XT.w[o0][2], XT.w[o0][2]}, rr[s0 + 2], a0);
        a0 = __builtin_elementwise_fma((v2f){XT.w[o0][3], XT.w[o0][3]}, rr[s0 + 3], a0);
        v2f a1 = rr[s1] * (v2f){XT.w[o1][0], XT.w[o1][0]};
        a1 = __builtin_elementwise_fma((v2f){XT.w[o1][1], XT.w[o1][1]}, rr[s1 + 1], a1);
        a1 = __builtin_elementwise_fma((v2f){XT.w[o1][2], XT.w[o1][2]}, rr[s1 + 2], a1);
        a1 = __builtin_elementwise_fma((v2f){XT.w[o1][3], XT.w[o1][3]}, rr[s1 + 3], a1);
        float4 st = {a0.x, a0.y, a1.x, a1.y};
        *(float4*)(dst + 2 * i) = st;               // ds_write_b128, 16B-aligned
    }
}

// ---- y-value for (col pair, hh): bit-identical chain used by pass and rescan ----
__device__ __forceinline__ v2f yv(const v2f* __restrict__ c, int hh) {
    const int ph = hh % 12, b = hh / 12;
    const int i0 = 7 * b + YT.d[ph] + 2;            // in [0,31] after unroll const-fold
    v2f acc = c[i0] * (v2f){YT.w[ph][0], YT.w[ph][0]};
    acc = __builtin_elementwise_fma((v2f){YT.w[ph][1], YT.w[ph][1]}, c[i0 + 1], acc);
    acc = __builtin_elementwise_fma((v2f){YT.w[ph][2], YT.w[ph][2]}, c[i0 + 2], acc);
    acc = __builtin_elementwise_fma((v2f){YT.w[ph][3], YT.w[ph][3]}, c[i0 + 3], acc);
    return acc;
}

__global__ __launch_bounds__(NT)
void _Keypointer_kernel(const float* __restrict__ masks,
                        const float* __restrict__ boxes,
                        float* __restrict__ out) {
    __shared__ __align__(16) v2f tmp[TROWS * RST];  // 47,040 B
    __shared__ v2f wmax[3];
    __shared__ int candp[2];

    const int t   = threadIdx.x;
    const int bm0 = 2 * blockIdx.x;
    const int g   = t >> 6;                         // col group (wave-uniform)
    const int w   = t & 63;

    // ---- phase 1: every lane identical work; pads produced by edge/extra lanes ----
    const int srcrow = min(max(w - 2, 0), HIN - 1);
    const int phys   = min(w, TROWS - 1);           // lanes 60..63 dup lane 59 (same data)
    const float* r0 = masks + (size_t)bm0 * (HIN * WIN) + srcrow * WIN;
    const float* r1 = r0 + HIN * WIN;
    v2f* dst = tmp + phys * RST + 32 * g;
    if      (g == 0) p1_cols<0>(r0, r1, dst);
    else if (g == 1) p1_cols<1>(r0, r1, dst);
    else             p1_cols<2>(r0, r1, dst);

    if (t == 0) { candp[0] = 0x7fffffff; candp[1] = 0x7fffffff; }
    __syncthreads();

    // ---- phase 2: thread = (col, h-half), both maps packed in v2f ----
    const int half = (t >= 96) ? 1 : 0;
    const int col  = t - 96 * half;
    const int h0   = 48 * half;
    const v2f* cb  = tmp + (28 * half) * RST + col;
    v2f c[32];
#pragma unroll
    for (int i = 0; i < 32; ++i) c[i] = cb[i * RST];   // ds_read_b64, imm offsets

    v2f vmax = {-INFINITY, -INFINITY};
#pragma unroll
    for (int hh = 0; hh < 48; ++hh)
        vmax = __builtin_elementwise_max(vmax, yv(c, hh));

    // block max per map
    float m0 = vmax.x, m1 = vmax.y;
#pragma unroll
    for (int off = 32; off > 0; off >>= 1) {
        m0 = fmaxf(m0, __shfl_down(m0, off, 64));
        m1 = fmaxf(m1, __shfl_down(m1, off, 64));
    }
    if (w == 0) wmax[g] = (v2f){m0, m1};
    __syncthreads();

    const float M0 = fmaxf(fmaxf(wmax[0].x, wmax[1].x), wmax[2].x);
    const float M1 = fmaxf(fmaxf(wmax[0].y, wmax[1].y), wmax[2].y);

    // sparse rescan: only threads whose column contained the max participate
    if (vmax.x == M0 || vmax.y == M1) {
        int c0 = 0x7fffffff, c1 = 0x7fffffff;
#pragma unroll
        for (int hh = 0; hh < 48; ++hh) {
            v2f a = yv(c, hh);                      // bit-identical recompute
            int fp = (h0 + hh) * OUTS + col;
            if (a.x == M0) c0 = min(c0, fp);
            if (a.y == M1) c1 = min(c1, fp);
        }
        if (c0 != 0x7fffffff) atomicMin(&candp[0], c0);
        if (c1 != 0x7fffffff) atomicMin(&candp[1], c1);
    }
    __syncthreads();

    if (t < 2) {
        const int map = bm0 + t;
        const float M = t ? M1 : M0;
        const int bp  = candp[t];
        const int r = map / K_, k = map - r * K_;
        const int y = bp / OUTS, x = bp - y * OUTS;
        const float b0f = boxes[r * 4 + 0], b1f = boxes[r * 4 + 1];
        const float b2f = boxes[r * 4 + 2], b3f = boxes[r * 4 + 3];
        const float corr0 = fmaxf(b2f - b0f, 1.0f) / (float)OUTS;
        const float corr1 = fmaxf(b3f - b1f, 1.0f) / (float)OUTS;
        const float p0 = ((float)y + 0.5f) * corr0 + b0f;
        const float p1 = ((float)x + 0.5f) * corr1 + b1f;
        out[(r * 3 + 0) * K_ + k] = p0;
        out[(r * 3 + 1) * K_ + k] = p1;
        out[(r * 3 + 2) * K_ + k] = 1.0f;
        out[R_ * 3 * K_ + r * K_ + k] = M;
    }
}

extern "C" void kernel_launch(void* const* d_in, const int* in_sizes, int n_in,
                              void* d_out, int out_size, void* d_ws, size_t ws_size,
                              hipStream_t stream) {
    const float* masks = (const float*)d_in[0];
    const float* boxes = (const float*)d_in[1];
    float* out = (float*)d_out;
    _Keypointer_kernel<<<NMAP / 2, NT, 0, stream>>>(masks, boxes, out);
}